// Round 11
// baseline (377.544 us; speedup 1.0000x reference)
//
#include <hip/hip_runtime.h>
#include <hip/hip_bf16.h>
#include <hip/hip_fp16.h>
#include <math.h>

// ---------------------------------------------------------------------------
// GRAPH_VAE_V3: GCN-VAE encoder + inner-product decoder.
// R11: merged-branch mm1 (x staged once, W1 fp16 LDS) and mm2 (a2h rows staged
// once, W2 fp16 LDS); decoder uses v_dot2_f32_f16.  Aggs at gather roofline.
// ---------------------------------------------------------------------------

typedef _Float16 hf2 __attribute__((ext_vector_type(2)));
static __device__ __forceinline__ hf2 as_hf2(unsigned u) {
    union { unsigned u; hf2 h; } c; c.u = u; return c.h;
}

__global__ void zero_int_k(int* __restrict__ p, int n) {
    int i = blockIdx.x * blockDim.x + threadIdx.x;
    if (i < n) p[i] = 0;
}

__global__ void count_dst_k(const int* __restrict__ ei, int* __restrict__ cnt, int E) {
    int e = blockIdx.x * blockDim.x + threadIdx.x;
    if (e < E) atomicAdd(&cnt[ei[E + e]], 1);
}

__global__ void compute_dis_k(const int* __restrict__ cnt, float* __restrict__ dis, int n) {
    int i = blockIdx.x * blockDim.x + threadIdx.x;
    if (i < n) dis[i] = rsqrtf((float)cnt[i] + 1.0f);
}

// ---- 3-phase parallel scan ----
__global__ void scan1_k(const int* __restrict__ cnt, int* __restrict__ row_ptr,
                        int* __restrict__ bsum, int n) {
    __shared__ int wsum[16];
    int tid = threadIdx.x, lane = tid & 63, wv = tid >> 6;
    int i = blockIdx.x * 1024 + tid;
    int v = (i < n) ? cnt[i] : 0;
    int x = v;
#pragma unroll
    for (int off = 1; off < 64; off <<= 1) {
        int t = __shfl_up(x, off, 64);
        if (lane >= off) x += t;
    }
    if (lane == 63) wsum[wv] = x;
    __syncthreads();
    if (wv == 0 && lane < 16) {
        int y = wsum[lane];
#pragma unroll
        for (int off = 1; off < 16; off <<= 1) {
            int t = __shfl_up(y, off, 64);
            if (lane >= off) y += t;
        }
        wsum[lane] = y;
    }
    __syncthreads();
    int incl = x + ((wv == 0) ? 0 : wsum[wv - 1]);
    if (i < n) row_ptr[i + 1] = incl;
    if (tid == 1023) bsum[blockIdx.x] = incl;
}

__global__ void scan2_k(int* __restrict__ bsum, int nb) {
    int lane = threadIdx.x;
    int v = (lane < nb) ? bsum[lane] : 0;
    int x = v;
#pragma unroll
    for (int off = 1; off < 64; off <<= 1) {
        int t = __shfl_up(x, off, 64);
        if (lane >= off) x += t;
    }
    if (lane < nb) bsum[lane] = x - v;
}

__global__ void scan3_k(const int* __restrict__ cnt, int* __restrict__ row_ptr,
                        const int* __restrict__ bsum, int* __restrict__ woff, int n) {
    int i = blockIdx.x * 1024 + threadIdx.x;
    if (i == 0) row_ptr[0] = 0;
    if (i < n) {
        int r = row_ptr[i + 1] + bsum[blockIdx.x];
        row_ptr[i + 1] = r;
        woff[i] = r - cnt[i];
    }
}

__global__ void scatter_edges_k(const int* __restrict__ ei, int* __restrict__ woff,
                                int* __restrict__ src_sorted, int E) {
    int e = blockIdx.x * blockDim.x + threadIdx.x;
    if (e < E) {
        int s = ei[e];
        int d = ei[E + e];
        int pos = atomicAdd(&woff[d], 1);
        src_sorted[pos] = s;
    }
}

// mm1 merged: both branches from one staged x tile.  out fp16 interleaved,
// prescaled by dis.  K=128, OUT=64.  LDS: W fp16 32KB + A 8KB.
__global__ __launch_bounds__(256, 4) void mm1_k(
        const float* __restrict__ A, const float* __restrict__ WA,
        const float* __restrict__ WB, __half* __restrict__ HH,
        const float* __restrict__ dis, int n) {
    constexpr int K = 128, OUT = 64, TX = 16, TY = 16, TM = 64, KC = 32, KC4 = 8;
    __shared__ __half2 w_lds[2][K * OUT / 2];  // 2 x 4096 half2
    __shared__ float a_lds[TM * KC];

    int tid = threadIdx.x;
    for (int idx = tid; idx < K * OUT; idx += 256) {  // K*OUT = 8192 = 2 branches x 4096
        int b = idx >> 12, i2 = idx & 4095;
        float2 w = ((const float2*)(b ? WB : WA))[i2];
        w_lds[b][i2] = __floats2half2_rn(w.x, w.y);
    }

    int row0 = blockIdx.x * TM;
    int tx = tid % TX, ty = tid / TX;

    float4 acc[2][4];
#pragma unroll
    for (int b = 0; b < 2; ++b)
#pragma unroll
        for (int i = 0; i < 4; ++i) acc[b][i] = make_float4(0.f, 0.f, 0.f, 0.f);

    int abase[4], akey[4];
#pragma unroll
    for (int i = 0; i < 4; ++i) {
        int r = ty * 4 + i;
        abase[i] = r * KC;
        akey[i]  = (r >> 2) & 7;
    }

    for (int kc = 0; kc < K; kc += KC) {
        __syncthreads();
        for (int f4 = tid; f4 < TM * KC4; f4 += 256) {
            int row = f4 >> 3, col4 = f4 & 7;
            float4 v = make_float4(0.f, 0.f, 0.f, 0.f);
            if (row0 + row < n)
                v = *(const float4*)&A[(size_t)(row0 + row) * K + kc + (col4 << 2)];
            *(float4*)&a_lds[row * KC + ((col4 ^ ((row >> 2) & 7)) << 2)] = v;
        }
        __syncthreads();

#pragma unroll
        for (int k = 0; k < KC; k += 4) {
            int k4 = k >> 2;
            float af[4][4];
#pragma unroll
            for (int i = 0; i < 4; ++i) {
                float4 a = *(const float4*)&a_lds[abase[i] + ((k4 ^ akey[i]) << 2)];
                af[i][0] = a.x; af[i][1] = a.y; af[i][2] = a.z; af[i][3] = a.w;
            }
#pragma unroll
            for (int j = 0; j < 4; ++j) {
                int widx = (kc + k + j) * (OUT / 2) + 2 * tx;
#pragma unroll
                for (int b = 0; b < 2; ++b) {
                    float2 f0 = __half22float2(w_lds[b][widx]);
                    float2 f1 = __half22float2(w_lds[b][widx + 1]);
#pragma unroll
                    for (int i = 0; i < 4; ++i) {
                        acc[b][i].x += af[i][j] * f0.x;
                        acc[b][i].y += af[i][j] * f0.y;
                        acc[b][i].z += af[i][j] * f1.x;
                        acc[b][i].w += af[i][j] * f1.y;
                    }
                }
            }
        }
    }

#pragma unroll
    for (int i = 0; i < 4; ++i) {
        int r = row0 + ty * 4 + i;
        if (r < n) {
            float dsc = dis[r];
#pragma unroll
            for (int b = 0; b < 2; ++b) {
                float4 o = acc[b][i];
                __half2 h0 = __floats2half2_rn(o.x * dsc, o.y * dsc);
                __half2 h1 = __floats2half2_rn(o.z * dsc, o.w * dsc);
                uint2 u = make_uint2(*(unsigned*)&h0, *(unsigned*)&h1);
                *(uint2*)&HH[(size_t)r * 128 + b * 64 + tx * 4] = u;
            }
        }
    }
}

// mm2 merged: a2h interleaved rows staged once (fp16->fp32), branch b uses
// cols b*64..  W2 fp16 LDS.  bias+relu, fp16 out.  K=64/branch, OUT=128.
__global__ __launch_bounds__(256, 3) void mm2_k(
        const __half* __restrict__ A, const float* __restrict__ WA,
        const float* __restrict__ WB, const float* __restrict__ bA,
        const float* __restrict__ bB, __half* __restrict__ HA,
        __half* __restrict__ HB, int n) {
    constexpr int K = 64, OUT = 128, TX = 32, TM = 32;
    __shared__ __half2 w_lds[2][K * OUT / 2];  // 2 x 4096 half2 = 32KB
    __shared__ float a_lds[TM * 128];          // 16KB

    int tid = threadIdx.x;
    for (int idx = tid; idx < K * OUT; idx += 256) {
        int b = idx >> 12, i2 = idx & 4095;
        float2 w = ((const float2*)(b ? WB : WA))[i2];
        w_lds[b][i2] = __floats2half2_rn(w.x, w.y);
    }

    int row0 = blockIdx.x * TM;
    // stage A rows (128 halves each) once
    for (int it = tid; it < TM * 16; it += 256) {
        int row = it >> 4, u8 = it & 15;
        float f[8] = {0.f, 0.f, 0.f, 0.f, 0.f, 0.f, 0.f, 0.f};
        if (row0 + row < n) {
            uint4 u = *(const uint4*)&A[(size_t)(row0 + row) * 128 + u8 * 8];
            const __half2* p = (const __half2*)&u;
#pragma unroll
            for (int i = 0; i < 4; ++i) {
                float2 t = __half22float2(p[i]);
                f[2 * i] = t.x; f[2 * i + 1] = t.y;
            }
        }
        int key = row & 15;
        *(float4*)&a_lds[row * 128 + (((2 * u8) ^ key) << 2)] =
            make_float4(f[0], f[1], f[2], f[3]);
        *(float4*)&a_lds[row * 128 + (((2 * u8 + 1) ^ key) << 2)] =
            make_float4(f[4], f[5], f[6], f[7]);
    }
    __syncthreads();

    int tx = tid % TX, ty = tid / TX;

    float4 acc[2][4];
#pragma unroll
    for (int b = 0; b < 2; ++b)
#pragma unroll
        for (int i = 0; i < 4; ++i) acc[b][i] = make_float4(0.f, 0.f, 0.f, 0.f);

#pragma unroll 4
    for (int k4 = 0; k4 < K / 4; ++k4) {
        float af[2][4][4];
#pragma unroll
        for (int b = 0; b < 2; ++b)
#pragma unroll
            for (int i = 0; i < 4; ++i) {
                int r = ty * 4 + i, key = r & 15;
                float4 a = *(const float4*)&a_lds[r * 128 + (((b * 16 + k4) ^ key) << 2)];
                af[b][i][0] = a.x; af[b][i][1] = a.y;
                af[b][i][2] = a.z; af[b][i][3] = a.w;
            }
#pragma unroll
        for (int j = 0; j < 4; ++j) {
            int widx = (4 * k4 + j) * (OUT / 2) + 2 * tx;
#pragma unroll
            for (int b = 0; b < 2; ++b) {
                float2 f0 = __half22float2(w_lds[b][widx]);
                float2 f1 = __half22float2(w_lds[b][widx + 1]);
#pragma unroll
                for (int i = 0; i < 4; ++i) {
                    acc[b][i].x += af[b][i][j] * f0.x;
                    acc[b][i].y += af[b][i][j] * f0.y;
                    acc[b][i].z += af[b][i][j] * f1.x;
                    acc[b][i].w += af[b][i][j] * f1.y;
                }
            }
        }
    }

#pragma unroll
    for (int i = 0; i < 4; ++i) {
        int r = row0 + ty * 4 + i;
        if (r < n) {
#pragma unroll
            for (int b = 0; b < 2; ++b) {
                float4 bb = ((const float4*)(b ? bB : bA))[tx];
                float4 o = acc[b][i];
                o.x = fmaxf(o.x + bb.x, 0.f);
                o.y = fmaxf(o.y + bb.y, 0.f);
                o.z = fmaxf(o.z + bb.z, 0.f);
                o.w = fmaxf(o.w + bb.w, 0.f);
                __half2 h0 = __floats2half2_rn(o.x, o.y);
                __half2 h1 = __floats2half2_rn(o.z, o.w);
                uint2 u = make_uint2(*(unsigned*)&h0, *(unsigned*)&h1);
                __half* H = b ? HB : HA;
                *(uint2*)&H[(size_t)r * 128 + tx * 4] = u;
            }
        }
    }
}

// Branch-pair matmul (kept for mm3), K-chunked A staging, fp16 A input,
// fp16 out with dis prescale.
template <int K, int OUT>
__global__ __launch_bounds__(256, 4) void mm3_k(
        const __half* __restrict__ AAh, const __half* __restrict__ ABh, int lda,
        const float* __restrict__ WA, const float* __restrict__ WB,
        __half* __restrict__ HH, const float* __restrict__ dis,
        int ldh, int offhA, int offhB, int n) {
    constexpr int TX = OUT / 4;
    constexpr int TY = 256 / TX;
    constexpr int TM = TY * 4;
    constexpr int KC = 32, KC8 = 4;
    __shared__ float w_lds[K * OUT];
    __shared__ float a_lds[TM * KC];

    int by = blockIdx.y;
    const __half* Ah = by ? ABh : AAh;
    const float* W = by ? WB : WA;
    int offh = by ? offhB : offhA;

    int tid = threadIdx.x;
    for (int idx = tid; idx < K * OUT / 4; idx += 256)
        ((float4*)w_lds)[idx] = ((const float4*)W)[idx];

    int row0 = blockIdx.x * TM;
    int tx = tid % TX, ty = tid / TX;

    float4 acc[4];
#pragma unroll
    for (int i = 0; i < 4; ++i) acc[i] = make_float4(0.f, 0.f, 0.f, 0.f);

    int abase[4], akey[4];
#pragma unroll
    for (int i = 0; i < 4; ++i) {
        int r = ty * 4 + i;
        abase[i] = r * KC;
        akey[i]  = (r >> 2) & 7;
    }

    for (int kc = 0; kc < K; kc += KC) {
        __syncthreads();
        for (int f8 = tid; f8 < TM * KC8; f8 += 256) {
            int row = f8 / KC8, col8 = f8 % KC8;
            float f[8] = {0.f, 0.f, 0.f, 0.f, 0.f, 0.f, 0.f, 0.f};
            if (row0 + row < n) {
                uint4 u = *(const uint4*)&Ah[(size_t)(row0 + row) * lda + kc + col8 * 8];
                const __half2* p = (const __half2*)&u;
#pragma unroll
                for (int i = 0; i < 4; ++i) {
                    float2 t = __half22float2(p[i]);
                    f[2 * i] = t.x; f[2 * i + 1] = t.y;
                }
            }
            int key = (row >> 2) & 7;
            *(float4*)&a_lds[row * KC + (((2 * col8) ^ key) << 2)] =
                make_float4(f[0], f[1], f[2], f[3]);
            *(float4*)&a_lds[row * KC + (((2 * col8 + 1) ^ key) << 2)] =
                make_float4(f[4], f[5], f[6], f[7]);
        }
        __syncthreads();

#pragma unroll
        for (int k = 0; k < KC; k += 4) {
            int k4 = k >> 2;
            float af[4][4];
#pragma unroll
            for (int i = 0; i < 4; ++i) {
                float4 a = *(const float4*)&a_lds[abase[i] + ((k4 ^ akey[i]) << 2)];
                af[i][0] = a.x; af[i][1] = a.y; af[i][2] = a.z; af[i][3] = a.w;
            }
#pragma unroll
            for (int j = 0; j < 4; ++j) {
                float4 wv = ((const float4*)w_lds)[(kc + k + j) * TX + tx];
#pragma unroll
                for (int i = 0; i < 4; ++i) {
                    acc[i].x += af[i][j] * wv.x;
                    acc[i].y += af[i][j] * wv.y;
                    acc[i].z += af[i][j] * wv.z;
                    acc[i].w += af[i][j] * wv.w;
                }
            }
        }
    }

#pragma unroll
    for (int i = 0; i < 4; ++i) {
        int r = row0 + ty * 4 + i;
        if (r < n) {
            float dsc = dis[r];
            float4 o = acc[i];
            __half2 h0 = __floats2half2_rn(o.x * dsc, o.y * dsc);
            __half2 h1 = __floats2half2_rn(o.z * dsc, o.w * dsc);
            uint2 u = make_uint2(*(unsigned*)&h0, *(unsigned*)&h1);
            *(uint2*)&HH[(size_t)r * ldh + offh + tx * 4] = u;
        }
    }
}

// Dual-branch CSR aggregation over dis-prescaled fp16 rows [mu64|ls64] (256B).
// Packed fp16 accumulate, fp32 epilogue.  MODE 0/1/2 as before.
template <int MODE>
__global__ void agg2h_k(const __half* __restrict__ h, const float* __restrict__ dis,
                        const int* __restrict__ row_ptr, const int* __restrict__ srcs,
                        const float* __restrict__ bM, const float* __restrict__ bL,
                        const float* __restrict__ eps,
                        __half* __restrict__ oH,
                        float* __restrict__ oM, float* __restrict__ oL,
                        __half* __restrict__ zh, int n) {
    int wid  = (int)((blockIdx.x * (size_t)blockDim.x + threadIdx.x) >> 6);
    int lane = threadIdx.x & 63;
    if (wid >= n) return;
    int g = lane >> 4;
    int q = lane & 15;
    const __half* hq = h + 8 * q;

    __half2 acc2[4];
    if (g == 0) {
        uint4 r = *(const uint4*)&hq[(size_t)wid << 7];
        const __half2* hp = (const __half2*)&r;
#pragma unroll
        for (int i = 0; i < 4; ++i) acc2[i] = hp[i];
    } else {
        __half2 z2 = __float2half2_rn(0.f);
#pragma unroll
        for (int i = 0; i < 4; ++i) acc2[i] = z2;
    }

    int beg = row_ptr[wid], end = row_ptr[wid + 1];
    for (int cb = beg; cb < end; cb += 64) {
        int m = end - cb;
        if (m > 64) m = 64;
        int sv = 0;
        if (lane < m) sv = srcs[cb + lane];
        int j = 0;
        for (; j + 16 <= m; j += 16) {
            int s0 = __shfl(sv, j + g, 64);
            int s1 = __shfl(sv, j + 4 + g, 64);
            int s2 = __shfl(sv, j + 8 + g, 64);
            int s3 = __shfl(sv, j + 12 + g, 64);
            uint4 r0 = *(const uint4*)&hq[(size_t)s0 << 7];
            uint4 r1 = *(const uint4*)&hq[(size_t)s1 << 7];
            uint4 r2 = *(const uint4*)&hq[(size_t)s2 << 7];
            uint4 r3 = *(const uint4*)&hq[(size_t)s3 << 7];
            const __half2* p0 = (const __half2*)&r0;
            const __half2* p1 = (const __half2*)&r1;
            const __half2* p2 = (const __half2*)&r2;
            const __half2* p3 = (const __half2*)&r3;
#pragma unroll
            for (int i = 0; i < 4; ++i)
                acc2[i] = __hadd2(acc2[i],
                          __hadd2(__hadd2(p0[i], p1[i]), __hadd2(p2[i], p3[i])));
        }
        for (; j + 8 <= m; j += 8) {
            int s0 = __shfl(sv, j + g, 64);
            int s1 = __shfl(sv, j + 4 + g, 64);
            uint4 r0 = *(const uint4*)&hq[(size_t)s0 << 7];
            uint4 r1 = *(const uint4*)&hq[(size_t)s1 << 7];
            const __half2* p0 = (const __half2*)&r0;
            const __half2* p1 = (const __half2*)&r1;
#pragma unroll
            for (int i = 0; i < 4; ++i)
                acc2[i] = __hadd2(acc2[i], __hadd2(p0[i], p1[i]));
        }
        for (; j < m; j += 4) {
            int idx = j + g;
            int s0 = __shfl(sv, (idx < m) ? idx : j, 64);
            if (idx < m) {
                uint4 r0 = *(const uint4*)&hq[(size_t)s0 << 7];
                const __half2* p0 = (const __half2*)&r0;
#pragma unroll
                for (int i = 0; i < 4; ++i) acc2[i] = __hadd2(acc2[i], p0[i]);
            }
        }
    }

#pragma unroll
    for (int i = 0; i < 4; ++i) {
        int u0 = *reinterpret_cast<int*>(&acc2[i]);
        int v0 = __shfl_xor(u0, 16, 64);
        acc2[i] = __hadd2(acc2[i], *reinterpret_cast<__half2*>(&v0));
        int u1 = *reinterpret_cast<int*>(&acc2[i]);
        int v1 = __shfl_xor(u1, 32, 64);
        acc2[i] = __hadd2(acc2[i], *reinterpret_cast<__half2*>(&v1));
    }

    float di = dis[wid];
    float acc[8];
#pragma unroll
    for (int i = 0; i < 4; ++i) {
        float2 f = __half22float2(acc2[i]);
        acc[2 * i]     = f.x * di;
        acc[2 * i + 1] = f.y * di;
    }

    if (MODE == 0) {
        if (g == 0) {
            __half2 hh[4];
#pragma unroll
            for (int i = 0; i < 4; ++i) hh[i] = __floats2half2_rn(acc[2 * i], acc[2 * i + 1]);
            *(uint4*)&oH[(size_t)wid * 128 + 8 * q] = *(uint4*)hh;
        }
    } else if (MODE == 1) {
        if (g == 0) {
            const float* bs = (q < 8) ? bM + 8 * q : bL + 8 * q - 64;
            __half2 hh[4];
#pragma unroll
            for (int i = 0; i < 8; i += 2) {
                float a0 = fmaxf(acc[i] + bs[i], 0.f) * di;
                float a1 = fmaxf(acc[i + 1] + bs[i + 1], 0.f) * di;
                hh[i >> 1] = __floats2half2_rn(a0, a1);
            }
            *(uint4*)&oH[(size_t)wid * 128 + 8 * q] = *(uint4*)hh;
        }
    } else {
        const float* bs = (q < 8) ? bM + 8 * q : bL + 8 * q - 64;
        float act[8];
#pragma unroll
        for (int i = 0; i < 8; ++i) {
            float a = fmaxf(acc[i] + bs[i], 0.f);
            if (q >= 8) a = fminf(a, 10.f);
            act[i] = a;
        }
        float lsv[8];
#pragma unroll
        for (int i = 0; i < 8; ++i) lsv[i] = __shfl(act[i], lane + 8, 64);
        if (g == 0) {
            size_t ob = (size_t)wid * 64;
            if (q < 8) {
                *(float4*)&oM[ob + 8 * q]     = make_float4(act[0], act[1], act[2], act[3]);
                *(float4*)&oM[ob + 8 * q + 4] = make_float4(act[4], act[5], act[6], act[7]);
                float4 e0 = *(const float4*)&eps[ob + 8 * q];
                float4 e1 = *(const float4*)&eps[ob + 8 * q + 4];
                float zz[8];
                zz[0] = fmaf(e0.x, expf(lsv[0]), act[0]);
                zz[1] = fmaf(e0.y, expf(lsv[1]), act[1]);
                zz[2] = fmaf(e0.z, expf(lsv[2]), act[2]);
                zz[3] = fmaf(e0.w, expf(lsv[3]), act[3]);
                zz[4] = fmaf(e1.x, expf(lsv[4]), act[4]);
                zz[5] = fmaf(e1.y, expf(lsv[5]), act[5]);
                zz[6] = fmaf(e1.z, expf(lsv[6]), act[6]);
                zz[7] = fmaf(e1.w, expf(lsv[7]), act[7]);
                __half2 zh4[4];
#pragma unroll
                for (int i = 0; i < 4; ++i) zh4[i] = __floats2half2_rn(zz[2 * i], zz[2 * i + 1]);
                *(uint4*)&zh[ob + 8 * q] = *(uint4*)zh4;
            } else {
                int qq = q - 8;
                *(float4*)&oL[ob + 8 * qq]     = make_float4(act[0], act[1], act[2], act[3]);
                *(float4*)&oL[ob + 8 * qq + 4] = make_float4(act[4], act[5], act[6], act[7]);
            }
        }
    }
}

// adj[e] = sigmoid( dot(z[src], z[dst]) ): 16 lanes/edge, fp16 z, fdot2 accumulate
__global__ void decoder_k(const int* __restrict__ ei, const __half* __restrict__ zh,
                          float* __restrict__ adj, int E) {
    int t = blockIdx.x * 256 + threadIdx.x;
    int e = t >> 4;
    int q = threadIdx.x & 15;
    if (e >= E) return;
    int s = ei[e];
    int d = ei[E + e];
    const uint2* z2 = (const uint2*)zh;
    uint2 ua = z2[(size_t)s * 16 + q];
    uint2 ub = z2[(size_t)d * 16 + q];
    float p = 0.f;
#if defined(__has_builtin) && __has_builtin(__builtin_amdgcn_fdot2)
    p = __builtin_amdgcn_fdot2(as_hf2(ua.x), as_hf2(ub.x), p, false);
    p = __builtin_amdgcn_fdot2(as_hf2(ua.y), as_hf2(ub.y), p, false);
#else
    {
        const __half2* pa = (const __half2*)&ua;
        const __half2* pb = (const __half2*)&ub;
#pragma unroll
        for (int i = 0; i < 2; ++i) {
            float2 fa = __half22float2(pa[i]);
            float2 fb = __half22float2(pb[i]);
            p = fmaf(fa.x, fb.x, p);
            p = fmaf(fa.y, fb.y, p);
        }
    }
#endif
    p += __shfl_xor(p, 8);
    p += __shfl_xor(p, 4);
    p += __shfl_xor(p, 2);
    p += __shfl_xor(p, 1);
    if (q == 0) adj[e] = 1.f / (1.f + expf(-p));
}

extern "C" void kernel_launch(void* const* d_in, const int* in_sizes, int n_in,
                              void* d_out, int out_size, void* d_ws, size_t ws_size,
                              hipStream_t stream) {
    const float* x   = (const float*)d_in[0];
    const int*   ei  = (const int*)d_in[1];
    const float* eps = (const float*)d_in[2];
    const float* w_mu1 = (const float*)d_in[3];
    const float* b_mu1 = (const float*)d_in[4];
    const float* w_mu2 = (const float*)d_in[5];
    const float* b_mu2 = (const float*)d_in[6];
    const float* w_mu3 = (const float*)d_in[7];
    const float* b_mu3 = (const float*)d_in[8];
    const float* w_ls1 = (const float*)d_in[9];
    const float* b_ls1 = (const float*)d_in[10];
    const float* w_ls2 = (const float*)d_in[11];
    const float* b_ls2 = (const float*)d_in[12];
    const float* w_ls3 = (const float*)d_in[13];
    const float* b_ls3 = (const float*)d_in[14];

    const int N = in_sizes[0] / 128;
    const int E = in_sizes[1] / 2;
    const size_t NB = (size_t)N * 128;

    float* out = (float*)d_out;
    float* adj = out;
    float* mu  = out + E;
    float* ls  = out + E + (size_t)N * 64;

    float* ws = (float*)d_ws;
    __half* hpA  = (__half*)ws;
    __half* a2h  = (__half*)ws;
    __half* hpB  = (__half*)(ws + NB);
    __half* h2mu = (__half*)(ws + NB);
    __half* h2ls = h2mu + (size_t)N * 128;
    __half* zh   = (__half*)(ws + NB);
    float* c0 = ws + 2 * NB;
    const size_t P = 50176;
    float* dis         = c0;
    int*   cnt         = (int*)(c0 + P);
    int*   row_ptr     = (int*)(c0 + 2 * P);
    int*   woff        = (int*)(c0 + 3 * P);
    int*   bsum        = (int*)(c0 + 4 * P);
    int*   src_sorted  = (int*)(c0 + 4 * P + 256);

    const int nscan = (N + 1023) / 1024;

    // ---- CSR build ----
    zero_int_k<<<(N + 255) / 256, 256, 0, stream>>>(cnt, N);
    count_dst_k<<<(E + 255) / 256, 256, 0, stream>>>(ei, cnt, E);
    compute_dis_k<<<(N + 255) / 256, 256, 0, stream>>>(cnt, dis, N);
    scan1_k<<<nscan, 1024, 0, stream>>>(cnt, row_ptr, bsum, N);
    scan2_k<<<1, 64, 0, stream>>>(bsum, nscan);
    scan3_k<<<nscan, 1024, 0, stream>>>(cnt, row_ptr, bsum, woff, N);
    scatter_edges_k<<<(E + 255) / 256, 256, 0, stream>>>(ei, woff, src_sorted, E);

    const int aggBlocks = (int)(((size_t)N * 64 + 255) / 256);

    // layer 1: G1' = dis*(x@W1) -> hpA (merged branches); h1' -> hpB
    mm1_k<<<(N + 63) / 64, 256, 0, stream>>>(x, w_mu1, w_ls1, hpA, dis, N);
    agg2h_k<1><<<aggBlocks, 256, 0, stream>>>(hpA, dis, row_ptr, src_sorted,
                                              b_mu1, b_ls1, nullptr, hpB,
                                              nullptr, nullptr, nullptr, N);

    // layer 2: a2 = dis*S2 -> a2h; h2 = relu(a2@W2+b2) -> h2mu/h2ls (merged)
    agg2h_k<0><<<aggBlocks, 256, 0, stream>>>(hpB, dis, row_ptr, src_sorted,
                                              nullptr, nullptr, nullptr, a2h,
                                              nullptr, nullptr, nullptr, N);
    mm2_k<<<(N + 31) / 32, 256, 0, stream>>>(a2h, w_mu2, w_ls2, b_mu2, b_ls2,
                                             h2mu, h2ls, N);

    // layer 3: G3' = dis*(h2@W3) -> hpA; final agg -> mu, ls, zh
    dim3 g64((N + 63) / 64, 2);
    mm3_k<128, 64><<<g64, 256, 0, stream>>>(h2mu, h2ls, 128, w_mu3, w_ls3,
                                            hpA, dis, 128, 0, 64, N);
    agg2h_k<2><<<aggBlocks, 256, 0, stream>>>(hpA, dis, row_ptr, src_sorted,
                                              b_mu3, b_ls3, eps, nullptr,
                                              mu, ls, zh, N);

    // decode
    decoder_k<<<(int)(((size_t)E * 16 + 255) / 256), 256, 0, stream>>>(ei, zh, adj, E);
}

// Round 12
// 272.329 us; speedup vs baseline: 1.3864x; 1.3864x over previous
//
#include <hip/hip_runtime.h>
#include <hip/hip_bf16.h>
#include <hip/hip_fp16.h>
#include <math.h>

// ---------------------------------------------------------------------------
// GRAPH_VAE_V3: GCN-VAE encoder + inner-product decoder.
// R12: revert to R10's proven split-branch matmul2_k (merged-branch mm1/mm2
// regressed 13x via scratch/codegen pathology); keep fdot2 decoder from R11.
// ---------------------------------------------------------------------------

typedef _Float16 hf2 __attribute__((ext_vector_type(2)));
static __device__ __forceinline__ hf2 as_hf2(unsigned u) {
    union { unsigned u; hf2 h; } c; c.u = u; return c.h;
}

__global__ void zero_int_k(int* __restrict__ p, int n) {
    int i = blockIdx.x * blockDim.x + threadIdx.x;
    if (i < n) p[i] = 0;
}

__global__ void count_dst_k(const int* __restrict__ ei, int* __restrict__ cnt, int E) {
    int e = blockIdx.x * blockDim.x + threadIdx.x;
    if (e < E) atomicAdd(&cnt[ei[E + e]], 1);
}

__global__ void compute_dis_k(const int* __restrict__ cnt, float* __restrict__ dis, int n) {
    int i = blockIdx.x * blockDim.x + threadIdx.x;
    if (i < n) dis[i] = rsqrtf((float)cnt[i] + 1.0f);
}

// ---- 3-phase parallel scan ----
__global__ void scan1_k(const int* __restrict__ cnt, int* __restrict__ row_ptr,
                        int* __restrict__ bsum, int n) {
    __shared__ int wsum[16];
    int tid = threadIdx.x, lane = tid & 63, wv = tid >> 6;
    int i = blockIdx.x * 1024 + tid;
    int v = (i < n) ? cnt[i] : 0;
    int x = v;
#pragma unroll
    for (int off = 1; off < 64; off <<= 1) {
        int t = __shfl_up(x, off, 64);
        if (lane >= off) x += t;
    }
    if (lane == 63) wsum[wv] = x;
    __syncthreads();
    if (wv == 0 && lane < 16) {
        int y = wsum[lane];
#pragma unroll
        for (int off = 1; off < 16; off <<= 1) {
            int t = __shfl_up(y, off, 64);
            if (lane >= off) y += t;
        }
        wsum[lane] = y;
    }
    __syncthreads();
    int incl = x + ((wv == 0) ? 0 : wsum[wv - 1]);
    if (i < n) row_ptr[i + 1] = incl;
    if (tid == 1023) bsum[blockIdx.x] = incl;
}

__global__ void scan2_k(int* __restrict__ bsum, int nb) {
    int lane = threadIdx.x;
    int v = (lane < nb) ? bsum[lane] : 0;
    int x = v;
#pragma unroll
    for (int off = 1; off < 64; off <<= 1) {
        int t = __shfl_up(x, off, 64);
        if (lane >= off) x += t;
    }
    if (lane < nb) bsum[lane] = x - v;
}

__global__ void scan3_k(const int* __restrict__ cnt, int* __restrict__ row_ptr,
                        const int* __restrict__ bsum, int* __restrict__ woff, int n) {
    int i = blockIdx.x * 1024 + threadIdx.x;
    if (i == 0) row_ptr[0] = 0;
    if (i < n) {
        int r = row_ptr[i + 1] + bsum[blockIdx.x];
        row_ptr[i + 1] = r;
        woff[i] = r - cnt[i];
    }
}

__global__ void scatter_edges_k(const int* __restrict__ ei, int* __restrict__ woff,
                                int* __restrict__ src_sorted, int E) {
    int e = blockIdx.x * blockDim.x + threadIdx.x;
    if (e < E) {
        int s = ei[e];
        int d = ei[E + e];
        int pos = atomicAdd(&woff[d], 1);
        src_sorted[pos] = s;
    }
}

// Branch-pair matmul (R10-proven), K-chunked A staging (KC=32), fp16 output.
// AH=1: A is fp16 (converted to fp32 during LDS staging).
// EPI=1: bias+relu.  PRE=1: multiply by dis[r] before fp16 store.
template <int K, int OUT, int EPI, int PRE, int AH>
__global__ __launch_bounds__(256, 4) void matmul2_k(
        const void* __restrict__ AAv, const void* __restrict__ ABv, int lda,
        int offaA, int offaB,
        const float* __restrict__ WA, const float* __restrict__ WB,
        const float* __restrict__ bA, const float* __restrict__ bB,
        __half* __restrict__ HHA, __half* __restrict__ HHB,
        const float* __restrict__ dis,
        int ldh, int offhA, int offhB, int n) {
    constexpr int TX = OUT / 4;
    constexpr int TY = 256 / TX;
    constexpr int TM = TY * 4;
    constexpr int KC = 32, KC4 = 8, KC8 = 4;
    __shared__ float w_lds[K * OUT];
    __shared__ float a_lds[TM * KC];

    int by = blockIdx.y;
    const float*  Af = (const float*)(by ? ABv : AAv);
    const __half* Ah = (const __half*)(by ? ABv : AAv);
    const float* W  = by ? WB : WA;
    const float* bi = by ? bB : bA;
    __half*      HH = by ? HHB : HHA;
    int offa = by ? offaB : offaA;
    int offh = by ? offhB : offhA;

    int tid = threadIdx.x;
    for (int idx = tid; idx < K * OUT / 4; idx += 256)
        ((float4*)w_lds)[idx] = ((const float4*)W)[idx];

    int row0 = blockIdx.x * TM;
    int tx = tid % TX;
    int ty = tid / TX;

    float4 acc[4];
#pragma unroll
    for (int i = 0; i < 4; ++i) acc[i] = make_float4(0.f, 0.f, 0.f, 0.f);

    int abase[4], akey[4];
#pragma unroll
    for (int i = 0; i < 4; ++i) {
        int r = ty * 4 + i;
        abase[i] = r * KC;
        akey[i]  = (r >> 2) & 7;
    }

    for (int kc = 0; kc < K; kc += KC) {
        __syncthreads();
        if constexpr (AH) {
            for (int f8 = tid; f8 < TM * KC8; f8 += 256) {
                int row  = f8 / KC8;
                int col8 = f8 % KC8;
                float f[8] = {0.f, 0.f, 0.f, 0.f, 0.f, 0.f, 0.f, 0.f};
                if (row0 + row < n) {
                    uint4 u = *(const uint4*)&Ah[(size_t)(row0 + row) * lda + offa + kc + col8 * 8];
                    const __half2* p = (const __half2*)&u;
#pragma unroll
                    for (int i = 0; i < 4; ++i) {
                        float2 t = __half22float2(p[i]);
                        f[2 * i] = t.x; f[2 * i + 1] = t.y;
                    }
                }
                int key = (row >> 2) & 7;
                *(float4*)&a_lds[row * KC + (((2 * col8) ^ key) << 2)] =
                    make_float4(f[0], f[1], f[2], f[3]);
                *(float4*)&a_lds[row * KC + (((2 * col8 + 1) ^ key) << 2)] =
                    make_float4(f[4], f[5], f[6], f[7]);
            }
        } else {
            for (int f4 = tid; f4 < TM * KC4; f4 += 256) {
                int row  = f4 >> 3;
                int col4 = f4 & 7;
                float4 v = make_float4(0.f, 0.f, 0.f, 0.f);
                if (row0 + row < n)
                    v = *(const float4*)&Af[(size_t)(row0 + row) * lda + offa + kc + (col4 << 2)];
                *(float4*)&a_lds[row * KC + ((col4 ^ ((row >> 2) & 7)) << 2)] = v;
            }
        }
        __syncthreads();

#pragma unroll
        for (int k = 0; k < KC; k += 4) {
            int k4 = k >> 2;
            float af[4][4];
#pragma unroll
            for (int i = 0; i < 4; ++i) {
                float4 a = *(const float4*)&a_lds[abase[i] + ((k4 ^ akey[i]) << 2)];
                af[i][0] = a.x; af[i][1] = a.y; af[i][2] = a.z; af[i][3] = a.w;
            }
#pragma unroll
            for (int j = 0; j < 4; ++j) {
                float4 wv = ((const float4*)w_lds)[(kc + k + j) * TX + tx];
#pragma unroll
                for (int i = 0; i < 4; ++i) {
                    acc[i].x += af[i][j] * wv.x;
                    acc[i].y += af[i][j] * wv.y;
                    acc[i].z += af[i][j] * wv.z;
                    acc[i].w += af[i][j] * wv.w;
                }
            }
        }
    }

#pragma unroll
    for (int i = 0; i < 4; ++i) {
        int r = row0 + ty * 4 + i;
        if (r < n) {
            float4 o = acc[i];
            if (EPI == 1) {
                float4 b = ((const float4*)bi)[tx];
                o.x = fmaxf(o.x + b.x, 0.f);
                o.y = fmaxf(o.y + b.y, 0.f);
                o.z = fmaxf(o.z + b.z, 0.f);
                o.w = fmaxf(o.w + b.w, 0.f);
            }
            float dsc = (PRE == 1) ? dis[r] : 1.f;
            __half2 h0 = __floats2half2_rn(o.x * dsc, o.y * dsc);
            __half2 h1 = __floats2half2_rn(o.z * dsc, o.w * dsc);
            uint2 u = make_uint2(*(unsigned*)&h0, *(unsigned*)&h1);
            *(uint2*)&HH[(size_t)r * ldh + offh + tx * 4] = u;
        }
    }
}

// Dual-branch CSR aggregation over dis-prescaled fp16 rows [mu64|ls64] (256B).
// Packed fp16 accumulate (v_pk_add_f16), fp32 epilogue.
// MODE 0: fp16(dis*S) -> oH      MODE 1: fp16(dis*relu(dis*S+b)) -> oH
// MODE 2: mu=relu(dis*S+b), ls=clamp, z=mu+eps*exp(ls) -> oM,oL (fp32) + zh (fp16)
template <int MODE>
__global__ void agg2h_k(const __half* __restrict__ h, const float* __restrict__ dis,
                        const int* __restrict__ row_ptr, const int* __restrict__ srcs,
                        const float* __restrict__ bM, const float* __restrict__ bL,
                        const float* __restrict__ eps,
                        __half* __restrict__ oH,
                        float* __restrict__ oM, float* __restrict__ oL,
                        __half* __restrict__ zh, int n) {
    int wid  = (int)((blockIdx.x * (size_t)blockDim.x + threadIdx.x) >> 6);
    int lane = threadIdx.x & 63;
    if (wid >= n) return;
    int g = lane >> 4;   // edge sub-group
    int q = lane & 15;   // channel octet
    const __half* hq = h + 8 * q;

    __half2 acc2[4];
    if (g == 0) {  // self-loop term
        uint4 r = *(const uint4*)&hq[(size_t)wid << 7];
        const __half2* hp = (const __half2*)&r;
#pragma unroll
        for (int i = 0; i < 4; ++i) acc2[i] = hp[i];
    } else {
        __half2 z2 = __float2half2_rn(0.f);
#pragma unroll
        for (int i = 0; i < 4; ++i) acc2[i] = z2;
    }

    int beg = row_ptr[wid], end = row_ptr[wid + 1];
    for (int cb = beg; cb < end; cb += 64) {
        int m = end - cb;
        if (m > 64) m = 64;
        int sv = 0;
        if (lane < m) sv = srcs[cb + lane];
        int j = 0;
        for (; j + 16 <= m; j += 16) {
            int s0 = __shfl(sv, j + g, 64);
            int s1 = __shfl(sv, j + 4 + g, 64);
            int s2 = __shfl(sv, j + 8 + g, 64);
            int s3 = __shfl(sv, j + 12 + g, 64);
            uint4 r0 = *(const uint4*)&hq[(size_t)s0 << 7];
            uint4 r1 = *(const uint4*)&hq[(size_t)s1 << 7];
            uint4 r2 = *(const uint4*)&hq[(size_t)s2 << 7];
            uint4 r3 = *(const uint4*)&hq[(size_t)s3 << 7];
            const __half2* p0 = (const __half2*)&r0;
            const __half2* p1 = (const __half2*)&r1;
            const __half2* p2 = (const __half2*)&r2;
            const __half2* p3 = (const __half2*)&r3;
#pragma unroll
            for (int i = 0; i < 4; ++i)
                acc2[i] = __hadd2(acc2[i],
                          __hadd2(__hadd2(p0[i], p1[i]), __hadd2(p2[i], p3[i])));
        }
        for (; j + 8 <= m; j += 8) {
            int s0 = __shfl(sv, j + g, 64);
            int s1 = __shfl(sv, j + 4 + g, 64);
            uint4 r0 = *(const uint4*)&hq[(size_t)s0 << 7];
            uint4 r1 = *(const uint4*)&hq[(size_t)s1 << 7];
            const __half2* p0 = (const __half2*)&r0;
            const __half2* p1 = (const __half2*)&r1;
#pragma unroll
            for (int i = 0; i < 4; ++i)
                acc2[i] = __hadd2(acc2[i], __hadd2(p0[i], p1[i]));
        }
        for (; j < m; j += 4) {
            int idx = j + g;
            int s0 = __shfl(sv, (idx < m) ? idx : j, 64);
            if (idx < m) {
                uint4 r0 = *(const uint4*)&hq[(size_t)s0 << 7];
                const __half2* p0 = (const __half2*)&r0;
#pragma unroll
                for (int i = 0; i < 4; ++i) acc2[i] = __hadd2(acc2[i], p0[i]);
            }
        }
    }

#pragma unroll
    for (int i = 0; i < 4; ++i) {
        int u0 = *reinterpret_cast<int*>(&acc2[i]);
        int v0 = __shfl_xor(u0, 16, 64);
        acc2[i] = __hadd2(acc2[i], *reinterpret_cast<__half2*>(&v0));
        int u1 = *reinterpret_cast<int*>(&acc2[i]);
        int v1 = __shfl_xor(u1, 32, 64);
        acc2[i] = __hadd2(acc2[i], *reinterpret_cast<__half2*>(&v1));
    }

    float di = dis[wid];
    float acc[8];
#pragma unroll
    for (int i = 0; i < 4; ++i) {
        float2 f = __half22float2(acc2[i]);
        acc[2 * i]     = f.x * di;
        acc[2 * i + 1] = f.y * di;
    }

    if (MODE == 0) {
        if (g == 0) {
            __half2 hh[4];
#pragma unroll
            for (int i = 0; i < 4; ++i) hh[i] = __floats2half2_rn(acc[2 * i], acc[2 * i + 1]);
            *(uint4*)&oH[(size_t)wid * 128 + 8 * q] = *(uint4*)hh;
        }
    } else if (MODE == 1) {
        if (g == 0) {
            const float* bs = (q < 8) ? bM + 8 * q : bL + 8 * q - 64;
            __half2 hh[4];
#pragma unroll
            for (int i = 0; i < 8; i += 2) {
                float a0 = fmaxf(acc[i] + bs[i], 0.f) * di;
                float a1 = fmaxf(acc[i + 1] + bs[i + 1], 0.f) * di;
                hh[i >> 1] = __floats2half2_rn(a0, a1);
            }
            *(uint4*)&oH[(size_t)wid * 128 + 8 * q] = *(uint4*)hh;
        }
    } else {
        const float* bs = (q < 8) ? bM + 8 * q : bL + 8 * q - 64;
        float act[8];
#pragma unroll
        for (int i = 0; i < 8; ++i) {
            float a = fmaxf(acc[i] + bs[i], 0.f);
            if (q >= 8) a = fminf(a, 10.f);
            act[i] = a;
        }
        float lsv[8];
#pragma unroll
        for (int i = 0; i < 8; ++i) lsv[i] = __shfl(act[i], lane + 8, 64);
        if (g == 0) {
            size_t ob = (size_t)wid * 64;
            if (q < 8) {
                *(float4*)&oM[ob + 8 * q]     = make_float4(act[0], act[1], act[2], act[3]);
                *(float4*)&oM[ob + 8 * q + 4] = make_float4(act[4], act[5], act[6], act[7]);
                float4 e0 = *(const float4*)&eps[ob + 8 * q];
                float4 e1 = *(const float4*)&eps[ob + 8 * q + 4];
                float zz[8];
                zz[0] = fmaf(e0.x, expf(lsv[0]), act[0]);
                zz[1] = fmaf(e0.y, expf(lsv[1]), act[1]);
                zz[2] = fmaf(e0.z, expf(lsv[2]), act[2]);
                zz[3] = fmaf(e0.w, expf(lsv[3]), act[3]);
                zz[4] = fmaf(e1.x, expf(lsv[4]), act[4]);
                zz[5] = fmaf(e1.y, expf(lsv[5]), act[5]);
                zz[6] = fmaf(e1.z, expf(lsv[6]), act[6]);
                zz[7] = fmaf(e1.w, expf(lsv[7]), act[7]);
                __half2 zh4[4];
#pragma unroll
                for (int i = 0; i < 4; ++i) zh4[i] = __floats2half2_rn(zz[2 * i], zz[2 * i + 1]);
                *(uint4*)&zh[ob + 8 * q] = *(uint4*)zh4;
            } else {
                int qq = q - 8;
                *(float4*)&oL[ob + 8 * qq]     = make_float4(act[0], act[1], act[2], act[3]);
                *(float4*)&oL[ob + 8 * qq + 4] = make_float4(act[4], act[5], act[6], act[7]);
            }
        }
    }
}

// adj[e] = sigmoid( dot(z[src], z[dst]) ): 16 lanes/edge, fp16 z, fdot2 accumulate
__global__ void decoder_k(const int* __restrict__ ei, const __half* __restrict__ zh,
                          float* __restrict__ adj, int E) {
    int t = blockIdx.x * 256 + threadIdx.x;
    int e = t >> 4;
    int q = threadIdx.x & 15;
    if (e >= E) return;
    int s = ei[e];
    int d = ei[E + e];
    const uint2* z2 = (const uint2*)zh;
    uint2 ua = z2[(size_t)s * 16 + q];
    uint2 ub = z2[(size_t)d * 16 + q];
    float p = 0.f;
#if defined(__has_builtin) && __has_builtin(__builtin_amdgcn_fdot2)
    p = __builtin_amdgcn_fdot2(as_hf2(ua.x), as_hf2(ub.x), p, false);
    p = __builtin_amdgcn_fdot2(as_hf2(ua.y), as_hf2(ub.y), p, false);
#else
    {
        const __half2* pa = (const __half2*)&ua;
        const __half2* pb = (const __half2*)&ub;
#pragma unroll
        for (int i = 0; i < 2; ++i) {
            float2 fa = __half22float2(pa[i]);
            float2 fb = __half22float2(pb[i]);
            p = fmaf(fa.x, fb.x, p);
            p = fmaf(fa.y, fb.y, p);
        }
    }
#endif
    p += __shfl_xor(p, 8);
    p += __shfl_xor(p, 4);
    p += __shfl_xor(p, 2);
    p += __shfl_xor(p, 1);
    if (q == 0) adj[e] = 1.f / (1.f + expf(-p));
}

extern "C" void kernel_launch(void* const* d_in, const int* in_sizes, int n_in,
                              void* d_out, int out_size, void* d_ws, size_t ws_size,
                              hipStream_t stream) {
    const float* x   = (const float*)d_in[0];
    const int*   ei  = (const int*)d_in[1];
    const float* eps = (const float*)d_in[2];
    const float* w_mu1 = (const float*)d_in[3];
    const float* b_mu1 = (const float*)d_in[4];
    const float* w_mu2 = (const float*)d_in[5];
    const float* b_mu2 = (const float*)d_in[6];
    const float* w_mu3 = (const float*)d_in[7];
    const float* b_mu3 = (const float*)d_in[8];
    const float* w_ls1 = (const float*)d_in[9];
    const float* b_ls1 = (const float*)d_in[10];
    const float* w_ls2 = (const float*)d_in[11];
    const float* b_ls2 = (const float*)d_in[12];
    const float* w_ls3 = (const float*)d_in[13];
    const float* b_ls3 = (const float*)d_in[14];

    const int N = in_sizes[0] / 128;
    const int E = in_sizes[1] / 2;
    const size_t NB = (size_t)N * 128;  // floats per region

    float* out = (float*)d_out;
    float* adj = out;                        // [E]
    float* mu  = out + E;                    // [N*64]
    float* ls  = out + E + (size_t)N * 64;   // [N*64]

    // region X (ws[0..NB)):   hpA (mm1/mm3 fp16 out)  |  a2h (MODE0 fp16 out)
    // region Y (ws[NB..2NB)): hpB (agg1 fp16 out)  |  h2mu+h2ls (mm2 fp16 out)  |  zh
    float* ws = (float*)d_ws;
    __half* hpA  = (__half*)ws;
    __half* a2h  = (__half*)ws;
    __half* hpB  = (__half*)(ws + NB);
    __half* h2mu = (__half*)(ws + NB);
    __half* h2ls = h2mu + (size_t)N * 128;
    __half* zh   = (__half*)(ws + NB);
    float* c0 = ws + 2 * NB;
    const size_t P = 50176;   // >= N+1
    float* dis         = c0;
    int*   cnt         = (int*)(c0 + P);
    int*   row_ptr     = (int*)(c0 + 2 * P);
    int*   woff        = (int*)(c0 + 3 * P);
    int*   bsum        = (int*)(c0 + 4 * P);
    int*   src_sorted  = (int*)(c0 + 4 * P + 256);

    const int nscan = (N + 1023) / 1024;

    // ---- CSR build ----
    zero_int_k<<<(N + 255) / 256, 256, 0, stream>>>(cnt, N);
    count_dst_k<<<(E + 255) / 256, 256, 0, stream>>>(ei, cnt, E);
    compute_dis_k<<<(N + 255) / 256, 256, 0, stream>>>(cnt, dis, N);
    scan1_k<<<nscan, 1024, 0, stream>>>(cnt, row_ptr, bsum, N);
    scan2_k<<<1, 64, 0, stream>>>(bsum, nscan);
    scan3_k<<<nscan, 1024, 0, stream>>>(cnt, row_ptr, bsum, woff, N);
    scatter_edges_k<<<(E + 255) / 256, 256, 0, stream>>>(ei, woff, src_sorted, E);

    const int aggBlocks = (int)(((size_t)N * 64 + 255) / 256);
    dim3 g64((N + 63) / 64, 2), g32((N + 31) / 32, 2);

    // layer 1: G1' = dis*(x@W1) -> hpA;  h1' = dis*relu(dis*S1+b) -> hpB
    matmul2_k<128, 64, 0, 1, 0><<<g64, 256, 0, stream>>>(
        x, x, 128, 0, 0, w_mu1, w_ls1, nullptr, nullptr, hpA, hpA, dis, 128, 0, 64, N);
    agg2h_k<1><<<aggBlocks, 256, 0, stream>>>(hpA, dis, row_ptr, src_sorted,
                                              b_mu1, b_ls1, nullptr, hpB,
                                              nullptr, nullptr, nullptr, N);

    // layer 2 (reordered): a2 = dis*S2 -> a2h (fp16);  h2 = relu(a2@W2+b2) -> h2mu/h2ls (fp16)
    agg2h_k<0><<<aggBlocks, 256, 0, stream>>>(hpB, dis, row_ptr, src_sorted,
                                              nullptr, nullptr, nullptr, a2h,
                                              nullptr, nullptr, nullptr, N);
    matmul2_k<64, 128, 1, 0, 1><<<g32, 256, 0, stream>>>(
        a2h, a2h, 128, 0, 64, w_mu2, w_ls2, b_mu2, b_ls2, h2mu, h2ls, dis, 128, 0, 0, N);

    // layer 3: G3' = dis*(h2@W3) -> hpA;  final agg -> mu, ls, zh
    matmul2_k<128, 64, 0, 1, 1><<<g64, 256, 0, stream>>>(
        h2mu, h2ls, 128, 0, 0, w_mu3, w_ls3, nullptr, nullptr, hpA, hpA, dis, 128, 0, 64, N);
    agg2h_k<2><<<aggBlocks, 256, 0, stream>>>(hpA, dis, row_ptr, src_sorted,
                                              b_mu3, b_ls3, eps, nullptr,
                                              mu, ls, zh, N);

    // decode (fp16 z rows)
    decoder_k<<<(int)(((size_t)E * 16 + 255) / 256), 256, 0, stream>>>(ei, zh, adj, E);
}

// Round 13
// 272.301 us; speedup vs baseline: 1.3865x; 1.0001x over previous
//
#include <hip/hip_runtime.h>
#include <hip/hip_bf16.h>
#include <hip/hip_fp16.h>
#include <math.h>

// ---------------------------------------------------------------------------
// GRAPH_VAE_V3: GCN-VAE encoder + inner-product decoder.
// R13: two-pass binned edge scatter (bucket = dst>>8, exact bases from
// row_ptr; LDS histogram in pass A) to kill random-write amplification;
// dis folded into scan1.  Rest identical to R12 (proven).
// ---------------------------------------------------------------------------

typedef _Float16 hf2 __attribute__((ext_vector_type(2)));
static __device__ __forceinline__ hf2 as_hf2(unsigned u) {
    union { unsigned u; hf2 h; } c; c.u = u; return c.h;
}

__global__ void zero_int_k(int* __restrict__ p, int n) {
    int i = blockIdx.x * blockDim.x + threadIdx.x;
    if (i < n) p[i] = 0;
}

__global__ void count_dst_k(const int* __restrict__ ei, int* __restrict__ cnt, int E) {
    int e = blockIdx.x * blockDim.x + threadIdx.x;
    if (e < E) atomicAdd(&cnt[ei[E + e]], 1);
}

// ---- 3-phase parallel scan (phase 1 also computes dis) ----
__global__ void scan1_k(const int* __restrict__ cnt, int* __restrict__ row_ptr,
                        int* __restrict__ bsum, float* __restrict__ dis, int n) {
    __shared__ int wsum[16];
    int tid = threadIdx.x, lane = tid & 63, wv = tid >> 6;
    int i = blockIdx.x * 1024 + tid;
    int v = (i < n) ? cnt[i] : 0;
    int x = v;
#pragma unroll
    for (int off = 1; off < 64; off <<= 1) {
        int t = __shfl_up(x, off, 64);
        if (lane >= off) x += t;
    }
    if (lane == 63) wsum[wv] = x;
    __syncthreads();
    if (wv == 0 && lane < 16) {
        int y = wsum[lane];
#pragma unroll
        for (int off = 1; off < 16; off <<= 1) {
            int t = __shfl_up(y, off, 64);
            if (lane >= off) y += t;
        }
        wsum[lane] = y;
    }
    __syncthreads();
    int incl = x + ((wv == 0) ? 0 : wsum[wv - 1]);
    if (i < n) {
        row_ptr[i + 1] = incl;
        dis[i] = rsqrtf((float)v + 1.0f);
    }
    if (tid == 1023) bsum[blockIdx.x] = incl;
}

__global__ void scan2_k(int* __restrict__ bsum, int nb) {
    int lane = threadIdx.x;
    int v = (lane < nb) ? bsum[lane] : 0;
    int x = v;
#pragma unroll
    for (int off = 1; off < 64; off <<= 1) {
        int t = __shfl_up(x, off, 64);
        if (lane >= off) x += t;
    }
    if (lane < nb) bsum[lane] = x - v;
}

__global__ void scan3_k(const int* __restrict__ cnt, int* __restrict__ row_ptr,
                        const int* __restrict__ bsum, int* __restrict__ woff, int n) {
    int i = blockIdx.x * 1024 + threadIdx.x;
    if (i == 0) row_ptr[0] = 0;
    if (i < n) {
        int r = row_ptr[i + 1] + bsum[blockIdx.x];
        row_ptr[i + 1] = r;
        woff[i] = r - cnt[i];
    }
}

// Pass A: bin edges by bucket = dst>>8.  Bucket b's final span is exactly
// [row_ptr[b<<8], row_ptr[(b+1)<<8]) — use it as the bin region (no extra
// scan).  Block-level LDS histogram -> one global atomic per (block,bucket).
__global__ __launch_bounds__(1024) void bin_edges_k(
        const int* __restrict__ ei, const int* __restrict__ row_ptr,
        int* __restrict__ bfill, int2* __restrict__ bin_sd, int E, int n) {
    __shared__ int hist[256];
    __shared__ int gbase[256];
    int tid = threadIdx.x;
    int nbuk = (n + 255) >> 8;
    for (int b = tid; b < nbuk; b += 1024) hist[b] = 0;
    __syncthreads();
    int e = blockIdx.x * 1024 + tid;
    int s = 0, d = 0, b = 0, lpos = 0;
    bool val = (e < E);
    if (val) {
        s = ei[e];
        d = ei[E + e];
        b = d >> 8;
        lpos = atomicAdd(&hist[b], 1);
    }
    __syncthreads();
    for (int bb = tid; bb < nbuk; bb += 1024) {
        int h = hist[bb];
        gbase[bb] = h ? atomicAdd(&bfill[bb], h) : 0;
    }
    __syncthreads();
    if (val) {
        int base = row_ptr[b << 8];
        bin_sd[base + gbase[b] + lpos] = make_int2(s, d);
    }
}

// Pass B: linear walk of the binned (bucket-ordered) edges; writes now
// cluster in each bucket's ~12KB src_sorted window -> L2-friendly.
__global__ void scatter2_k(const int2* __restrict__ bin_sd, int* __restrict__ woff,
                           int* __restrict__ src_sorted, int E) {
    int e = blockIdx.x * 256 + threadIdx.x;
    if (e < E) {
        int2 sd = bin_sd[e];
        int pos = atomicAdd(&woff[sd.y], 1);
        src_sorted[pos] = sd.x;
    }
}

// Branch-pair matmul (R10-proven), K-chunked A staging (KC=32), fp16 output.
// AH=1: A is fp16 (converted to fp32 during LDS staging).
// EPI=1: bias+relu.  PRE=1: multiply by dis[r] before fp16 store.
template <int K, int OUT, int EPI, int PRE, int AH>
__global__ __launch_bounds__(256, 4) void matmul2_k(
        const void* __restrict__ AAv, const void* __restrict__ ABv, int lda,
        int offaA, int offaB,
        const float* __restrict__ WA, const float* __restrict__ WB,
        const float* __restrict__ bA, const float* __restrict__ bB,
        __half* __restrict__ HHA, __half* __restrict__ HHB,
        const float* __restrict__ dis,
        int ldh, int offhA, int offhB, int n) {
    constexpr int TX = OUT / 4;
    constexpr int TY = 256 / TX;
    constexpr int TM = TY * 4;
    constexpr int KC = 32, KC4 = 8, KC8 = 4;
    __shared__ float w_lds[K * OUT];
    __shared__ float a_lds[TM * KC];

    int by = blockIdx.y;
    const float*  Af = (const float*)(by ? ABv : AAv);
    const __half* Ah = (const __half*)(by ? ABv : AAv);
    const float* W  = by ? WB : WA;
    const float* bi = by ? bB : bA;
    __half*      HH = by ? HHB : HHA;
    int offa = by ? offaB : offaA;
    int offh = by ? offhB : offhA;

    int tid = threadIdx.x;
    for (int idx = tid; idx < K * OUT / 4; idx += 256)
        ((float4*)w_lds)[idx] = ((const float4*)W)[idx];

    int row0 = blockIdx.x * TM;
    int tx = tid % TX;
    int ty = tid / TX;

    float4 acc[4];
#pragma unroll
    for (int i = 0; i < 4; ++i) acc[i] = make_float4(0.f, 0.f, 0.f, 0.f);

    int abase[4], akey[4];
#pragma unroll
    for (int i = 0; i < 4; ++i) {
        int r = ty * 4 + i;
        abase[i] = r * KC;
        akey[i]  = (r >> 2) & 7;
    }

    for (int kc = 0; kc < K; kc += KC) {
        __syncthreads();
        if constexpr (AH) {
            for (int f8 = tid; f8 < TM * KC8; f8 += 256) {
                int row  = f8 / KC8;
                int col8 = f8 % KC8;
                float f[8] = {0.f, 0.f, 0.f, 0.f, 0.f, 0.f, 0.f, 0.f};
                if (row0 + row < n) {
                    uint4 u = *(const uint4*)&Ah[(size_t)(row0 + row) * lda + offa + kc + col8 * 8];
                    const __half2* p = (const __half2*)&u;
#pragma unroll
                    for (int i = 0; i < 4; ++i) {
                        float2 t = __half22float2(p[i]);
                        f[2 * i] = t.x; f[2 * i + 1] = t.y;
                    }
                }
                int key = (row >> 2) & 7;
                *(float4*)&a_lds[row * KC + (((2 * col8) ^ key) << 2)] =
                    make_float4(f[0], f[1], f[2], f[3]);
                *(float4*)&a_lds[row * KC + (((2 * col8 + 1) ^ key) << 2)] =
                    make_float4(f[4], f[5], f[6], f[7]);
            }
        } else {
            for (int f4 = tid; f4 < TM * KC4; f4 += 256) {
                int row  = f4 >> 3;
                int col4 = f4 & 7;
                float4 v = make_float4(0.f, 0.f, 0.f, 0.f);
                if (row0 + row < n)
                    v = *(const float4*)&Af[(size_t)(row0 + row) * lda + offa + kc + (col4 << 2)];
                *(float4*)&a_lds[row * KC + ((col4 ^ ((row >> 2) & 7)) << 2)] = v;
            }
        }
        __syncthreads();

#pragma unroll
        for (int k = 0; k < KC; k += 4) {
            int k4 = k >> 2;
            float af[4][4];
#pragma unroll
            for (int i = 0; i < 4; ++i) {
                float4 a = *(const float4*)&a_lds[abase[i] + ((k4 ^ akey[i]) << 2)];
                af[i][0] = a.x; af[i][1] = a.y; af[i][2] = a.z; af[i][3] = a.w;
            }
#pragma unroll
            for (int j = 0; j < 4; ++j) {
                float4 wv = ((const float4*)w_lds)[(kc + k + j) * TX + tx];
#pragma unroll
                for (int i = 0; i < 4; ++i) {
                    acc[i].x += af[i][j] * wv.x;
                    acc[i].y += af[i][j] * wv.y;
                    acc[i].z += af[i][j] * wv.z;
                    acc[i].w += af[i][j] * wv.w;
                }
            }
        }
    }

#pragma unroll
    for (int i = 0; i < 4; ++i) {
        int r = row0 + ty * 4 + i;
        if (r < n) {
            float4 o = acc[i];
            if (EPI == 1) {
                float4 b = ((const float4*)bi)[tx];
                o.x = fmaxf(o.x + b.x, 0.f);
                o.y = fmaxf(o.y + b.y, 0.f);
                o.z = fmaxf(o.z + b.z, 0.f);
                o.w = fmaxf(o.w + b.w, 0.f);
            }
            float dsc = (PRE == 1) ? dis[r] : 1.f;
            __half2 h0 = __floats2half2_rn(o.x * dsc, o.y * dsc);
            __half2 h1 = __floats2half2_rn(o.z * dsc, o.w * dsc);
            uint2 u = make_uint2(*(unsigned*)&h0, *(unsigned*)&h1);
            *(uint2*)&HH[(size_t)r * ldh + offh + tx * 4] = u;
        }
    }
}

// Dual-branch CSR aggregation over dis-prescaled fp16 rows [mu64|ls64] (256B).
// Packed fp16 accumulate (v_pk_add_f16), fp32 epilogue.
// MODE 0: fp16(dis*S) -> oH      MODE 1: fp16(dis*relu(dis*S+b)) -> oH
// MODE 2: mu=relu(dis*S+b), ls=clamp, z=mu+eps*exp(ls) -> oM,oL (fp32) + zh (fp16)
template <int MODE>
__global__ void agg2h_k(const __half* __restrict__ h, const float* __restrict__ dis,
                        const int* __restrict__ row_ptr, const int* __restrict__ srcs,
                        const float* __restrict__ bM, const float* __restrict__ bL,
                        const float* __restrict__ eps,
                        __half* __restrict__ oH,
                        float* __restrict__ oM, float* __restrict__ oL,
                        __half* __restrict__ zh, int n) {
    int wid  = (int)((blockIdx.x * (size_t)blockDim.x + threadIdx.x) >> 6);
    int lane = threadIdx.x & 63;
    if (wid >= n) return;
    int g = lane >> 4;   // edge sub-group
    int q = lane & 15;   // channel octet
    const __half* hq = h + 8 * q;

    __half2 acc2[4];
    if (g == 0) {  // self-loop term
        uint4 r = *(const uint4*)&hq[(size_t)wid << 7];
        const __half2* hp = (const __half2*)&r;
#pragma unroll
        for (int i = 0; i < 4; ++i) acc2[i] = hp[i];
    } else {
        __half2 z2 = __float2half2_rn(0.f);
#pragma unroll
        for (int i = 0; i < 4; ++i) acc2[i] = z2;
    }

    int beg = row_ptr[wid], end = row_ptr[wid + 1];
    for (int cb = beg; cb < end; cb += 64) {
        int m = end - cb;
        if (m > 64) m = 64;
        int sv = 0;
        if (lane < m) sv = srcs[cb + lane];
        int j = 0;
        for (; j + 16 <= m; j += 16) {
            int s0 = __shfl(sv, j + g, 64);
            int s1 = __shfl(sv, j + 4 + g, 64);
            int s2 = __shfl(sv, j + 8 + g, 64);
            int s3 = __shfl(sv, j + 12 + g, 64);
            uint4 r0 = *(const uint4*)&hq[(size_t)s0 << 7];
            uint4 r1 = *(const uint4*)&hq[(size_t)s1 << 7];
            uint4 r2 = *(const uint4*)&hq[(size_t)s2 << 7];
            uint4 r3 = *(const uint4*)&hq[(size_t)s3 << 7];
            const __half2* p0 = (const __half2*)&r0;
            const __half2* p1 = (const __half2*)&r1;
            const __half2* p2 = (const __half2*)&r2;
            const __half2* p3 = (const __half2*)&r3;
#pragma unroll
            for (int i = 0; i < 4; ++i)
                acc2[i] = __hadd2(acc2[i],
                          __hadd2(__hadd2(p0[i], p1[i]), __hadd2(p2[i], p3[i])));
        }
        for (; j + 8 <= m; j += 8) {
            int s0 = __shfl(sv, j + g, 64);
            int s1 = __shfl(sv, j + 4 + g, 64);
            uint4 r0 = *(const uint4*)&hq[(size_t)s0 << 7];
            uint4 r1 = *(const uint4*)&hq[(size_t)s1 << 7];
            const __half2* p0 = (const __half2*)&r0;
            const __half2* p1 = (const __half2*)&r1;
#pragma unroll
            for (int i = 0; i < 4; ++i)
                acc2[i] = __hadd2(acc2[i], __hadd2(p0[i], p1[i]));
        }
        for (; j < m; j += 4) {
            int idx = j + g;
            int s0 = __shfl(sv, (idx < m) ? idx : j, 64);
            if (idx < m) {
                uint4 r0 = *(const uint4*)&hq[(size_t)s0 << 7];
                const __half2* p0 = (const __half2*)&r0;
#pragma unroll
                for (int i = 0; i < 4; ++i) acc2[i] = __hadd2(acc2[i], p0[i]);
            }
        }
    }

#pragma unroll
    for (int i = 0; i < 4; ++i) {
        int u0 = *reinterpret_cast<int*>(&acc2[i]);
        int v0 = __shfl_xor(u0, 16, 64);
        acc2[i] = __hadd2(acc2[i], *reinterpret_cast<__half2*>(&v0));
        int u1 = *reinterpret_cast<int*>(&acc2[i]);
        int v1 = __shfl_xor(u1, 32, 64);
        acc2[i] = __hadd2(acc2[i], *reinterpret_cast<__half2*>(&v1));
    }

    float di = dis[wid];
    float acc[8];
#pragma unroll
    for (int i = 0; i < 4; ++i) {
        float2 f = __half22float2(acc2[i]);
        acc[2 * i]     = f.x * di;
        acc[2 * i + 1] = f.y * di;
    }

    if (MODE == 0) {
        if (g == 0) {
            __half2 hh[4];
#pragma unroll
            for (int i = 0; i < 4; ++i) hh[i] = __floats2half2_rn(acc[2 * i], acc[2 * i + 1]);
            *(uint4*)&oH[(size_t)wid * 128 + 8 * q] = *(uint4*)hh;
        }
    } else if (MODE == 1) {
        if (g == 0) {
            const float* bs = (q < 8) ? bM + 8 * q : bL + 8 * q - 64;
            __half2 hh[4];
#pragma unroll
            for (int i = 0; i < 8; i += 2) {
                float a0 = fmaxf(acc[i] + bs[i], 0.f) * di;
                float a1 = fmaxf(acc[i + 1] + bs[i + 1], 0.f) * di;
                hh[i >> 1] = __floats2half2_rn(a0, a1);
            }
            *(uint4*)&oH[(size_t)wid * 128 + 8 * q] = *(uint4*)hh;
        }
    } else {
        const float* bs = (q < 8) ? bM + 8 * q : bL + 8 * q - 64;
        float act[8];
#pragma unroll
        for (int i = 0; i < 8; ++i) {
            float a = fmaxf(acc[i] + bs[i], 0.f);
            if (q >= 8) a = fminf(a, 10.f);
            act[i] = a;
        }
        float lsv[8];
#pragma unroll
        for (int i = 0; i < 8; ++i) lsv[i] = __shfl(act[i], lane + 8, 64);
        if (g == 0) {
            size_t ob = (size_t)wid * 64;
            if (q < 8) {
                *(float4*)&oM[ob + 8 * q]     = make_float4(act[0], act[1], act[2], act[3]);
                *(float4*)&oM[ob + 8 * q + 4] = make_float4(act[4], act[5], act[6], act[7]);
                float4 e0 = *(const float4*)&eps[ob + 8 * q];
                float4 e1 = *(const float4*)&eps[ob + 8 * q + 4];
                float zz[8];
                zz[0] = fmaf(e0.x, expf(lsv[0]), act[0]);
                zz[1] = fmaf(e0.y, expf(lsv[1]), act[1]);
                zz[2] = fmaf(e0.z, expf(lsv[2]), act[2]);
                zz[3] = fmaf(e0.w, expf(lsv[3]), act[3]);
                zz[4] = fmaf(e1.x, expf(lsv[4]), act[4]);
                zz[5] = fmaf(e1.y, expf(lsv[5]), act[5]);
                zz[6] = fmaf(e1.z, expf(lsv[6]), act[6]);
                zz[7] = fmaf(e1.w, expf(lsv[7]), act[7]);
                __half2 zh4[4];
#pragma unroll
                for (int i = 0; i < 4; ++i) zh4[i] = __floats2half2_rn(zz[2 * i], zz[2 * i + 1]);
                *(uint4*)&zh[ob + 8 * q] = *(uint4*)zh4;
            } else {
                int qq = q - 8;
                *(float4*)&oL[ob + 8 * qq]     = make_float4(act[0], act[1], act[2], act[3]);
                *(float4*)&oL[ob + 8 * qq + 4] = make_float4(act[4], act[5], act[6], act[7]);
            }
        }
    }
}

// adj[e] = sigmoid( dot(z[src], z[dst]) ): 16 lanes/edge, fp16 z, fdot2 accumulate
__global__ void decoder_k(const int* __restrict__ ei, const __half* __restrict__ zh,
                          float* __restrict__ adj, int E) {
    int t = blockIdx.x * 256 + threadIdx.x;
    int e = t >> 4;
    int q = threadIdx.x & 15;
    if (e >= E) return;
    int s = ei[e];
    int d = ei[E + e];
    const uint2* z2 = (const uint2*)zh;
    uint2 ua = z2[(size_t)s * 16 + q];
    uint2 ub = z2[(size_t)d * 16 + q];
    float p = 0.f;
#if defined(__has_builtin) && __has_builtin(__builtin_amdgcn_fdot2)
    p = __builtin_amdgcn_fdot2(as_hf2(ua.x), as_hf2(ub.x), p, false);
    p = __builtin_amdgcn_fdot2(as_hf2(ua.y), as_hf2(ub.y), p, false);
#else
    {
        const __half2* pa = (const __half2*)&ua;
        const __half2* pb = (const __half2*)&ub;
#pragma unroll
        for (int i = 0; i < 2; ++i) {
            float2 fa = __half22float2(pa[i]);
            float2 fb = __half22float2(pb[i]);
            p = fmaf(fa.x, fb.x, p);
            p = fmaf(fa.y, fb.y, p);
        }
    }
#endif
    p += __shfl_xor(p, 8);
    p += __shfl_xor(p, 4);
    p += __shfl_xor(p, 2);
    p += __shfl_xor(p, 1);
    if (q == 0) adj[e] = 1.f / (1.f + expf(-p));
}

extern "C" void kernel_launch(void* const* d_in, const int* in_sizes, int n_in,
                              void* d_out, int out_size, void* d_ws, size_t ws_size,
                              hipStream_t stream) {
    const float* x   = (const float*)d_in[0];
    const int*   ei  = (const int*)d_in[1];
    const float* eps = (const float*)d_in[2];
    const float* w_mu1 = (const float*)d_in[3];
    const float* b_mu1 = (const float*)d_in[4];
    const float* w_mu2 = (const float*)d_in[5];
    const float* b_mu2 = (const float*)d_in[6];
    const float* w_mu3 = (const float*)d_in[7];
    const float* b_mu3 = (const float*)d_in[8];
    const float* w_ls1 = (const float*)d_in[9];
    const float* b_ls1 = (const float*)d_in[10];
    const float* w_ls2 = (const float*)d_in[11];
    const float* b_ls2 = (const float*)d_in[12];
    const float* w_ls3 = (const float*)d_in[13];
    const float* b_ls3 = (const float*)d_in[14];

    const int N = in_sizes[0] / 128;
    const int E = in_sizes[1] / 2;
    const size_t NB = (size_t)N * 128;  // floats per region

    float* out = (float*)d_out;
    float* adj = out;                        // [E]
    float* mu  = out + E;                    // [N*64]
    float* ls  = out + E + (size_t)N * 64;   // [N*64]

    // region X (ws[0..NB)):   hpA (mm1/mm3 fp16 out)  |  a2h (MODE0 fp16 out)
    // region Y (ws[NB..2NB)): hpB (agg1 fp16 out)  |  h2mu+h2ls (mm2 fp16 out)  |  zh
    float* ws = (float*)d_ws;
    __half* hpA  = (__half*)ws;
    __half* a2h  = (__half*)ws;
    __half* hpB  = (__half*)(ws + NB);
    __half* h2mu = (__half*)(ws + NB);
    __half* h2ls = h2mu + (size_t)N * 128;
    __half* zh   = (__half*)(ws + NB);
    float* c0 = ws + 2 * NB;
    const size_t P  = 50176;   // >= N+1
    const size_t EP = 600064;  // >= E
    float* dis         = c0;                       // P floats
    int*   cnt         = (int*)(c0 + P);           // P ints, bfill right after
    int*   bfill       = cnt + P;                  // 256 ints
    int*   row_ptr     = (int*)(c0 + 2 * P + 256); // P ints
    int*   woff        = (int*)(c0 + 3 * P + 256); // P ints
    int*   bsum        = (int*)(c0 + 4 * P + 256); // 256 ints
    int*   src_sorted  = (int*)(c0 + 4 * P + 512); // EP ints
    int2*  bin_sd      = (int2*)(c0 + 4 * P + 512 + EP);  // E int2 (8B-aligned)

    const int nscan = (N + 1023) / 1024;

    // ---- CSR build ----
    zero_int_k<<<(int)((P + 256 + 255) / 256), 256, 0, stream>>>(cnt, (int)(P + 256));
    count_dst_k<<<(E + 255) / 256, 256, 0, stream>>>(ei, cnt, E);
    scan1_k<<<nscan, 1024, 0, stream>>>(cnt, row_ptr, bsum, dis, N);
    scan2_k<<<1, 64, 0, stream>>>(bsum, nscan);
    scan3_k<<<nscan, 1024, 0, stream>>>(cnt, row_ptr, bsum, woff, N);
    bin_edges_k<<<(E + 1023) / 1024, 1024, 0, stream>>>(ei, row_ptr, bfill, bin_sd, E, N);
    scatter2_k<<<(E + 255) / 256, 256, 0, stream>>>(bin_sd, woff, src_sorted, E);

    const int aggBlocks = (int)(((size_t)N * 64 + 255) / 256);
    dim3 g64((N + 63) / 64, 2), g32((N + 31) / 32, 2);

    // layer 1: G1' = dis*(x@W1) -> hpA;  h1' = dis*relu(dis*S1+b) -> hpB
    matmul2_k<128, 64, 0, 1, 0><<<g64, 256, 0, stream>>>(
        x, x, 128, 0, 0, w_mu1, w_ls1, nullptr, nullptr, hpA, hpA, dis, 128, 0, 64, N);
    agg2h_k<1><<<aggBlocks, 256, 0, stream>>>(hpA, dis, row_ptr, src_sorted,
                                              b_mu1, b_ls1, nullptr, hpB,
                                              nullptr, nullptr, nullptr, N);

    // layer 2 (reordered): a2 = dis*S2 -> a2h (fp16);  h2 = relu(a2@W2+b2) -> h2mu/h2ls (fp16)
    agg2h_k<0><<<aggBlocks, 256, 0, stream>>>(hpB, dis, row_ptr, src_sorted,
                                              nullptr, nullptr, nullptr, a2h,
                                              nullptr, nullptr, nullptr, N);
    matmul2_k<64, 128, 1, 0, 1><<<g32, 256, 0, stream>>>(
        a2h, a2h, 128, 0, 64, w_mu2, w_ls2, b_mu2, b_ls2, h2mu, h2ls, dis, 128, 0, 0, N);

    // layer 3: G3' = dis*(h2@W3) -> hpA;  final agg -> mu, ls, zh
    matmul2_k<128, 64, 0, 1, 1><<<g64, 256, 0, stream>>>(
        h2mu, h2ls, 128, 0, 0, w_mu3, w_ls3, nullptr, nullptr, hpA, hpA, dis, 128, 0, 64, N);
    agg2h_k<2><<<aggBlocks, 256, 0, stream>>>(hpA, dis, row_ptr, src_sorted,
                                              b_mu3, b_ls3, eps, nullptr,
                                              mu, ls, zh, N);

    // decode (fp16 z rows)
    decoder_k<<<(int)(((size_t)E * 16 + 255) / 256), 256, 0, stream>>>(ei, zh, adj, E);
}